// Round 3
// baseline (1850.924 us; speedup 1.0000x reference)
//
#include <hip/hip_runtime.h>

// CNF forward: 8 fixed dopri5 steps, 6 stages each, rows independent.
// One persistent kernel: 256 blocks x 512 threads; wave handles 16 rows.
// MFMA 16x16x32 bf16; weights in LDS; k's/state/ghv in registers (C-layout).
//
// R3: R1/R2's 2.3GB HBM traffic was private arrays (kp/ghvp/b1v) living in
// SCRATCH: dynamic indices (st-loop not unrolled) blocked SROA promotion.
// Fix: macro-unroll every loop touching a private array so all indices are
// literal constants -> frontend SROA promotes to registers. Structure/layout
// identical to R2 (proven correct, absmax 1.0 vs threshold 3.1).

typedef __bf16 bf16x8 __attribute__((ext_vector_type(8)));
typedef float  f32x4  __attribute__((ext_vector_type(4)));
typedef unsigned int u32;

#define MFMA16(a, b, c) __builtin_amdgcn_mfma_f32_16x16x32_bf16((a), (b), (c), 0, 0, 0)

__device__ __forceinline__ u32 bfbits(float x) {
    __bf16 b = (__bf16)x;                      // RNE fp32->bf16
    return (u32)__builtin_bit_cast(unsigned short, b);
}
__device__ __forceinline__ float frombits(u32 u16) {
    return __builtin_bit_cast(float, u16 << 16);
}
__device__ __forceinline__ u32 pack2(float lo, float hi) {
    return bfbits(lo) | (bfbits(hi) << 16);
}
__device__ __forceinline__ float fast_tanh(float x) {
    float e = __expf(2.0f * x);
    return 1.0f - 2.0f * __builtin_amdgcn_rcpf(e + 1.0f);
}

#define R8(M)  M(0) M(1) M(2) M(3) M(4) M(5) M(6) M(7)
#define R16(M) M(0) M(1) M(2) M(3) M(4) M(5) M(6) M(7) \
               M(8) M(9) M(10) M(11) M(12) M(13) M(14) M(15)

extern "C" __global__ __attribute__((amdgpu_waves_per_eu(2, 2))) void
__launch_bounds__(512)
cnf_kernel(const float* __restrict__ Yg, const float* __restrict__ Eg,
           const float* __restrict__ W1g, const float* __restrict__ b1g,
           const float* __restrict__ W2g, const float* __restrict__ b2g,
           float* __restrict__ Og)
{
    // ---- LDS (~109 KB; 1 WG/CU) ----
    __shared__ __align__(16) __bf16 sW1aT[256 * 72];   // [j][d] W1a^T, d-contig per j
    __shared__ __align__(16) __bf16 sW2U[256 * 72];    // phase1: W2 [j][d]; phase2: W2^T [d*264+j]
    __shared__ __align__(16) __bf16 sY[8][16 * 72];    // per-wave y stage buf [m][d]
    __shared__ __align__(16) __bf16 sH[8][16 * 40];    // per-wave h chunk [m][kloc 0..31]
    __shared__ __align__(16) float  sScr[8][16 * 17 + 4]; // per-wave transpose scratch

    const int tid  = threadIdx.x;
    const int wave = tid >> 6;
    const int lane = tid & 63;
    const int quad = lane >> 4;
    const int l16  = lane & 15;
    const int row0 = blockIdx.x * 128 + wave * 16;  // 16 rows per wave
    const int rr   = quad * 4;                      // C-layout row base (rows rr..rr+3)

    // ---------------- phase-1 weight staging ----------------
    for (int idx = tid; idx < 64 * 256; idx += 512) {         // W1a^T
        int d = idx >> 8, j = idx & 255;
        sW1aT[j * 72 + d] = (__bf16)W1g[idx];
    }
    for (int idx = tid; idx < 256 * 64; idx += 512) {         // W2 row-major
        int j = idx >> 6, d = idx & 63;
        sW2U[j * 72 + d] = (__bf16)W2g[idx];
    }
    __syncthreads();

    // bias / time-row / b2 in registers (constant-indexed only)
    float b1v[16], w1tv[16];
#define LDB1(jt) b1v[jt] = b1g[(jt) * 16 + l16]; w1tv[jt] = W1g[64 * 256 + (jt) * 16 + l16];
    R16(LDB1)
    float bb[4];
#define LDB2(nt) bb[nt] = b2g[(nt) * 16 + l16];
    LDB2(0) LDB2(1) LDB2(2) LDB2(3)

    __bf16* yb  = sY[wave];
    __bf16* hb  = sH[wave];
    float*  scr = sScr[wave];

    // ---------------- stage e into ybuf (wave-local) ----------------
#define LDE(i) \
    yb[(rr + ((i)&1)*2 + 0) * 72 + ((i)>>1)*16 + l16] = \
        (__bf16)Eg[(row0 + rr + ((i)&1)*2 + 0) * 64 + ((i)>>1)*16 + l16]; \
    yb[(rr + ((i)&1)*2 + 1) * 72 + ((i)>>1)*16 + l16] = \
        (__bf16)Eg[(row0 + rr + ((i)&1)*2 + 1) * 64 + ((i)>>1)*16 + l16];
    R8(LDE)

    // A-frags of e: A[m=l16][k=d], d-contig
    bf16x8 ae0 = *(const bf16x8*)(yb + l16 * 72 + quad * 8);
    bf16x8 ae1 = *(const bf16x8*)(yb + l16 * 72 + 32 + quad * 8);

    // ---------------- precompute ghv = (e@W1a) * (e@W2^T), C-layout regs ----------------
    u32 ghvp[32];  // [jt][pair], bf16x2; constant-indexed only
#define PRE(tt) { \
    f32x4 vacc = {0.f, 0.f, 0.f, 0.f}; \
    f32x4 gacc = {0.f, 0.f, 0.f, 0.f}; \
    bf16x8 wb0 = *(const bf16x8*)(sW1aT + ((tt)*16 + l16) * 72 + quad * 8); \
    bf16x8 wb1 = *(const bf16x8*)(sW1aT + ((tt)*16 + l16) * 72 + 32 + quad * 8); \
    vacc = MFMA16(ae0, wb0, vacc); \
    vacc = MFMA16(ae1, wb1, vacc); \
    bf16x8 aw0 = *(const bf16x8*)(sW2U + ((tt)*16 + l16) * 72 + quad * 8); \
    bf16x8 aw1 = *(const bf16x8*)(sW2U + ((tt)*16 + l16) * 72 + 32 + quad * 8); \
    gacc = MFMA16(aw0, ae0, gacc); \
    gacc = MFMA16(aw1, ae1, gacc); \
    scr[(rr + 0) * 17 + l16] = gacc[0]; \
    scr[(rr + 1) * 17 + l16] = gacc[1]; \
    scr[(rr + 2) * 17 + l16] = gacc[2]; \
    scr[(rr + 3) * 17 + l16] = gacc[3]; \
    __syncthreads(); \
    ghvp[(tt)*2 + 0] = pack2(scr[l16 * 17 + rr + 0] * vacc[0], \
                             scr[l16 * 17 + rr + 1] * vacc[1]); \
    ghvp[(tt)*2 + 1] = pack2(scr[l16 * 17 + rr + 2] * vacc[2], \
                             scr[l16 * 17 + rr + 3] * vacc[3]); \
    __syncthreads(); }
    R16(PRE)

    // ---------------- load z state (fp32, constant-indexed) ----------------
    float z[8][2];  // slot i = nt*2+pr: rows rr+(i&1)*2+{0,1}, col (i>>1)*16+l16
#define LDZ(i) \
    z[i][0] = Yg[(row0 + rr + ((i)&1)*2 + 0) * 64 + ((i)>>1)*16 + l16]; \
    z[i][1] = Yg[(row0 + rr + ((i)&1)*2 + 1) * 64 + ((i)>>1)*16 + l16];
    R8(LDZ)

    // ---------------- phase-2: overwrite union region with W2^T ----------------
    __syncthreads();
    for (int idx = tid; idx < 256 * 64; idx += 512) {
        int j = idx >> 6, d = idx & 63;
        sW2U[d * 264 + j] = (__bf16)W2g[idx];  // [d][j], j-contig per d
    }
    __syncthreads();

    const float dt = 0.125f;
    u32 kp[6][8];   // k_dz bf16-packed; constant-indexed only
    float lp0 = 0.f, lp1 = 0.f, lp2 = 0.f, lp3 = 0.f;

#define KLO(s, i) frombits(kp[s][i] & 0xffffu)
#define KHI(s, i) frombits(kp[s][i] >> 16)

#define STORE_Y(i, a0, a1) \
    yb[(rr + ((i)&1)*2 + 0) * 72 + ((i)>>1)*16 + l16] = (__bf16)(z[i][0] + dt*(a0)); \
    yb[(rr + ((i)&1)*2 + 1) * 72 + ((i)>>1)*16 + l16] = (__bf16)(z[i][1] + dt*(a1));

#define BUILD0(i) STORE_Y(i, 0.f, 0.f)
#define BUILD1(i) STORE_Y(i, 0.2f*KLO(0,i), 0.2f*KHI(0,i))
#define BUILD2(i) STORE_Y(i, 0.075f*KLO(0,i) + 0.225f*KLO(1,i), \
                             0.075f*KHI(0,i) + 0.225f*KHI(1,i))
#define BUILD3(i) STORE_Y(i, \
    (44.f/45.f)*KLO(0,i) + (-56.f/15.f)*KLO(1,i) + (32.f/9.f)*KLO(2,i), \
    (44.f/45.f)*KHI(0,i) + (-56.f/15.f)*KHI(1,i) + (32.f/9.f)*KHI(2,i))
#define BUILD4(i) STORE_Y(i, \
    (19372.f/6561.f)*KLO(0,i) + (-25360.f/2187.f)*KLO(1,i) + \
    (64448.f/6561.f)*KLO(2,i) + (-212.f/729.f)*KLO(3,i), \
    (19372.f/6561.f)*KHI(0,i) + (-25360.f/2187.f)*KHI(1,i) + \
    (64448.f/6561.f)*KHI(2,i) + (-212.f/729.f)*KHI(3,i))
#define BUILD5(i) STORE_Y(i, \
    (9017.f/3168.f)*KLO(0,i) + (-355.f/33.f)*KLO(1,i) + \
    (46732.f/5247.f)*KLO(2,i) + (49.f/176.f)*KLO(3,i) + (-5103.f/18656.f)*KLO(4,i), \
    (9017.f/3168.f)*KHI(0,i) + (-355.f/33.f)*KHI(1,i) + \
    (46732.f/5247.f)*KHI(2,i) + (49.f/176.f)*KHI(3,i) + (-5103.f/18656.f)*KHI(4,i))

#define JT_BODY(jt, hf) { \
    f32x4 ua = {0.f, 0.f, 0.f, 0.f}; \
    bf16x8 wb0 = *(const bf16x8*)(sW1aT + ((jt)*16 + l16) * 72 + quad * 8); \
    ua = MFMA16(a10, wb0, ua); \
    bf16x8 wb1 = *(const bf16x8*)(sW1aT + ((jt)*16 + l16) * 72 + 32 + quad * 8); \
    ua = MFMA16(a11, wb1, ua); \
    const float bw = b1v[jt] + ti * w1tv[jt]; \
    float h0 = fast_tanh(ua[0] + bw), h1 = fast_tanh(ua[1] + bw); \
    float h2 = fast_tanh(ua[2] + bw), h3 = fast_tanh(ua[3] + bw); \
    dv0 += frombits(ghvp[(jt)*2 + 0] & 0xffffu) * (1.f - h0*h0); \
    dv1 += frombits(ghvp[(jt)*2 + 0] >> 16)     * (1.f - h1*h1); \
    dv2 += frombits(ghvp[(jt)*2 + 1] & 0xffffu) * (1.f - h2*h2); \
    dv3 += frombits(ghvp[(jt)*2 + 1] >> 16)     * (1.f - h3*h3); \
    __bf16* hw = hb + (hf)*16 + l16; \
    hw[(rr + 0) * 40] = (__bf16)h0; hw[(rr + 1) * 40] = (__bf16)h1; \
    hw[(rr + 2) * 40] = (__bf16)h2; hw[(rr + 3) * 40] = (__bf16)h3; }

#define KK_BODY(kk2) { \
    bf16x8 a2  = *(const bf16x8*)(hb + l16 * 40 + quad * 8); \
    bf16x8 w20 = *(const bf16x8*)(sW2U + ( 0 + l16) * 264 + (kk2)*32 + quad * 8); \
    fa0 = MFMA16(a2, w20, fa0); \
    bf16x8 w21 = *(const bf16x8*)(sW2U + (16 + l16) * 264 + (kk2)*32 + quad * 8); \
    fa1 = MFMA16(a2, w21, fa1); \
    bf16x8 w22 = *(const bf16x8*)(sW2U + (32 + l16) * 264 + (kk2)*32 + quad * 8); \
    fa2 = MFMA16(a2, w22, fa2); \
    bf16x8 w23 = *(const bf16x8*)(sW2U + (48 + l16) * 264 + (kk2)*32 + quad * 8); \
    fa3 = MFMA16(a2, w23, fa3); }

#define CHUNK(kk2) JT_BODY(2*(kk2), 0) JT_BODY(2*(kk2)+1, 1) KK_BODY(kk2)

#define STAGE(st, CTI, DTB) { \
    const float ti = t0 + (CTI) * dt; \
    bf16x8 a10 = *(const bf16x8*)(yb + l16 * 72 + quad * 8); \
    bf16x8 a11 = *(const bf16x8*)(yb + l16 * 72 + 32 + quad * 8); \
    f32x4 fa0 = {0.f,0.f,0.f,0.f}, fa1 = {0.f,0.f,0.f,0.f}; \
    f32x4 fa2 = {0.f,0.f,0.f,0.f}, fa3 = {0.f,0.f,0.f,0.f}; \
    float dv0 = 0.f, dv1 = 0.f, dv2 = 0.f, dv3 = 0.f; \
    CHUNK(0) CHUNK(1) CHUNK(2) CHUNK(3) CHUNK(4) CHUNK(5) CHUNK(6) CHUNK(7) \
    kp[st][0] = pack2(fa0[0] + bb[0], fa0[1] + bb[0]); \
    kp[st][1] = pack2(fa0[2] + bb[0], fa0[3] + bb[0]); \
    kp[st][2] = pack2(fa1[0] + bb[1], fa1[1] + bb[1]); \
    kp[st][3] = pack2(fa1[2] + bb[1], fa1[3] + bb[1]); \
    kp[st][4] = pack2(fa2[0] + bb[2], fa2[1] + bb[2]); \
    kp[st][5] = pack2(fa2[2] + bb[2], fa2[3] + bb[2]); \
    kp[st][6] = pack2(fa3[0] + bb[3], fa3[1] + bb[3]); \
    kp[st][7] = pack2(fa3[2] + bb[3], fa3[3] + bb[3]); \
    dv0 += __shfl_xor(dv0, 1); dv0 += __shfl_xor(dv0, 2); \
    dv0 += __shfl_xor(dv0, 4); dv0 += __shfl_xor(dv0, 8); \
    dv1 += __shfl_xor(dv1, 1); dv1 += __shfl_xor(dv1, 2); \
    dv1 += __shfl_xor(dv1, 4); dv1 += __shfl_xor(dv1, 8); \
    dv2 += __shfl_xor(dv2, 1); dv2 += __shfl_xor(dv2, 2); \
    dv2 += __shfl_xor(dv2, 4); dv2 += __shfl_xor(dv2, 8); \
    dv3 += __shfl_xor(dv3, 1); dv3 += __shfl_xor(dv3, 2); \
    dv3 += __shfl_xor(dv3, 4); dv3 += __shfl_xor(dv3, 8); \
    lp0 -= (DTB) * dv0; lp1 -= (DTB) * dv1; \
    lp2 -= (DTB) * dv2; lp3 -= (DTB) * dv3; }

#define COMB(i) { \
    float s0 = (35.f/384.f)*KLO(0,i) + (500.f/1113.f)*KLO(2,i) + (125.f/192.f)*KLO(3,i) \
             + (-2187.f/6784.f)*KLO(4,i) + (11.f/84.f)*KLO(5,i); \
    float s1 = (35.f/384.f)*KHI(0,i) + (500.f/1113.f)*KHI(2,i) + (125.f/192.f)*KHI(3,i) \
             + (-2187.f/6784.f)*KHI(4,i) + (11.f/84.f)*KHI(5,i); \
    z[i][0] += dt * s0; z[i][1] += dt * s1; }

    for (int step = 0; step < 8; ++step) {
        const float t0 = dt * (float)step;
        R8(BUILD0) STAGE(0, 0.f,       dt*(35.f/384.f))
        R8(BUILD1) STAGE(1, 0.2f,      dt*0.f)
        R8(BUILD2) STAGE(2, 0.3f,      dt*(500.f/1113.f))
        R8(BUILD3) STAGE(3, 0.8f,      dt*(125.f/192.f))
        R8(BUILD4) STAGE(4, 8.f/9.f,   dt*(-2187.f/6784.f))
        R8(BUILD5) STAGE(5, 1.f,       dt*(11.f/84.f))
        R8(COMB)
    }

    // ---------------- epilogue: z out, log_px = log_pz - dlogp ----------------
    float ss0 = 0.f, ss1 = 0.f, ss2 = 0.f, ss3 = 0.f;
#define EPI(i) { \
    float v0 = z[i][0], v1 = z[i][1]; \
    Og[(row0 + rr + ((i)&1)*2 + 0) * 64 + ((i)>>1)*16 + l16] = v0; \
    Og[(row0 + rr + ((i)&1)*2 + 1) * 64 + ((i)>>1)*16 + l16] = v1; \
    if ((i) & 1) { ss2 += v0*v0; ss3 += v1*v1; } \
    else         { ss0 += v0*v0; ss1 += v1*v1; } }
    R8(EPI)

    ss0 += __shfl_xor(ss0, 1); ss0 += __shfl_xor(ss0, 2);
    ss0 += __shfl_xor(ss0, 4); ss0 += __shfl_xor(ss0, 8);
    ss1 += __shfl_xor(ss1, 1); ss1 += __shfl_xor(ss1, 2);
    ss1 += __shfl_xor(ss1, 4); ss1 += __shfl_xor(ss1, 8);
    ss2 += __shfl_xor(ss2, 1); ss2 += __shfl_xor(ss2, 2);
    ss2 += __shfl_xor(ss2, 4); ss2 += __shfl_xor(ss2, 8);
    ss3 += __shfl_xor(ss3, 1); ss3 += __shfl_xor(ss3, 2);
    ss3 += __shfl_xor(ss3, 4); ss3 += __shfl_xor(ss3, 8);
    if (l16 == 0) {
        const float CLOG = -58.8120661f;  // -32*ln(2*pi)
        Og[32768 * 64 + row0 + rr + 0] = CLOG - 0.5f * ss0 - lp0;
        Og[32768 * 64 + row0 + rr + 1] = CLOG - 0.5f * ss1 - lp1;
        Og[32768 * 64 + row0 + rr + 2] = CLOG - 0.5f * ss2 - lp2;
        Og[32768 * 64 + row0 + rr + 3] = CLOG - 0.5f * ss3 - lp3;
    }
}

extern "C" void kernel_launch(void* const* d_in, const int* in_sizes, int n_in,
                              void* d_out, int out_size, void* d_ws, size_t ws_size,
                              hipStream_t stream) {
    const float* Yg  = (const float*)d_in[0];
    const float* Eg  = (const float*)d_in[1];
    const float* W1g = (const float*)d_in[2];  // [65][256]
    const float* b1g = (const float*)d_in[3];
    const float* W2g = (const float*)d_in[4];  // [256][64]
    const float* b2g = (const float*)d_in[5];
    float* Og = (float*)d_out;                 // z (32768*64) then log_px (32768)
    cnf_kernel<<<dim3(256), dim3(512), 0, stream>>>(Yg, Eg, W1g, b1g, W2g, b2g, Og);
}

// Round 4
// 370.660 us; speedup vs baseline: 4.9936x; 4.9936x over previous
//
#include <hip/hip_runtime.h>

// CNF forward: 8 fixed dopri5 steps x 6 stages, rows independent.
// R4: wave-pair decomposition to fit a 128-VGPR budget (allocator is pinned
// at 128 regardless of launch-bounds/waves_per_eu attrs; R1-R3 all spilled
// GBs to scratch). Two waves share 16 rows: wave P owns output cols
// [P*32, P*32+32) and hidden units j in [P*128, P*128+128).
//   per-lane state: kp 24 u32 + z 8 f32 + ghvp 16 u32 + lp 4 + bb 2 ~= 60 regs
// h exchanges through a pair-shared LDS buffer; 2 __syncthreads per stage.
// 512 thr/block = 4 pairs = 64 rows; grid 512.

typedef __bf16 bf16x8 __attribute__((ext_vector_type(8)));
typedef float  f32x4  __attribute__((ext_vector_type(4)));
typedef unsigned int u32;

#define MFMA16(a, b, c) __builtin_amdgcn_mfma_f32_16x16x32_bf16((a), (b), (c), 0, 0, 0)

__device__ __forceinline__ u32 bfbits(float x) {
    __bf16 b = (__bf16)x;                      // RNE fp32->bf16
    return (u32)__builtin_bit_cast(unsigned short, b);
}
__device__ __forceinline__ float frombits(u32 u16) {
    return __builtin_bit_cast(float, u16 << 16);
}
__device__ __forceinline__ u32 pack2(float lo, float hi) {
    return bfbits(lo) | (bfbits(hi) << 16);
}
__device__ __forceinline__ float fast_tanh(float x) {
    float e = __expf(2.0f * x);
    return 1.0f - 2.0f * __builtin_amdgcn_rcpf(e + 1.0f);
}

extern "C" __global__ __attribute__((amdgpu_waves_per_eu(2, 2))) void
__launch_bounds__(512)
cnf_kernel(const float* __restrict__ Yg, const float* __restrict__ Eg,
           const float* __restrict__ W1g, const float* __restrict__ b1g,
           const float* __restrict__ W2g, const float* __restrict__ b2g,
           float* __restrict__ Og)
{
    // ---- LDS (~129 KB; 1 WG/CU -> 2 waves/EU) ----
    __shared__ __align__(16) __bf16 sW1aT[256 * 72];   // [j][d] W1a^T, d-contig
    __shared__ __align__(16) __bf16 sW2U[256 * 72];    // ph1: W2 [j*72+d]; ph2: W2^T [d*264+j]
    __shared__ __align__(16) __bf16 sY[4][16 * 72];    // per-PAIR y buf [row][d]
    __shared__ __align__(16) __bf16 sH[4][16 * 264];   // per-PAIR h buf [row][j]
    __shared__ __align__(16) float  sScr[8][16 * 17 + 4]; // per-wave transpose scratch
    __shared__ float sB1[256], sW1t[256], sB2[64];
    __shared__ float sRedSS[128], sRedLP[128];

    const int tid  = threadIdx.x;
    const int wave = tid >> 6;
    const int lane = tid & 63;
    const int quad = lane >> 4;
    const int l16  = lane & 15;
    const int P    = wave & 1;        // pair member: col/j half owner
    const int pair = wave >> 1;
    const int colb = P * 32;          // own output-col base
    const int jb   = P * 128;         // own hidden-j base
    const int row0 = blockIdx.x * 64 + pair * 16;
    const int rr   = quad * 4;        // C-layout row base

    // ---------------- phase-1 weight staging ----------------
    for (int idx = tid; idx < 64 * 256; idx += 512) {         // W1a^T
        int d = idx >> 8, j = idx & 255;
        sW1aT[j * 72 + d] = (__bf16)W1g[idx];
    }
    for (int idx = tid; idx < 256 * 64; idx += 512) {         // W2 row-major
        int j = idx >> 6, d = idx & 63;
        sW2U[j * 72 + d] = (__bf16)W2g[idx];
    }
    for (int j = tid; j < 256; j += 512) { sB1[j] = b1g[j]; sW1t[j] = W1g[64 * 256 + j]; }
    if (tid < 64) sB2[tid] = b2g[tid];
    __syncthreads();

    __bf16* yb  = sY[pair];
    __bf16* hb  = sH[pair];
    float*  scr = sScr[wave];

    // ---------------- stage e into yb (each wave writes its col half) ----------------
#define LDE(ct, rg) \
    yb[(rr + (rg)) * 72 + colb + (ct) * 16 + l16] = \
        (__bf16)Eg[(row0 + rr + (rg)) * 64 + colb + (ct) * 16 + l16];
    LDE(0,0) LDE(0,1) LDE(0,2) LDE(0,3) LDE(1,0) LDE(1,1) LDE(1,2) LDE(1,3)
    __syncthreads();

    // A/B frags of e: [m=l16][k=d], d-contig, full K=64
    bf16x8 ae0 = *(const bf16x8*)(yb + l16 * 72 + quad * 8);
    bf16x8 ae1 = *(const bf16x8*)(yb + l16 * 72 + 32 + quad * 8);

    // ---------------- precompute ghv = (e@W1a) * (e@W2^T) for own j-half ----------------
    u32 ghvp[16];  // [jt 0..7][pair], bf16x2; constant-indexed
#define PRE(jt) { \
    const int jrow = jb + (jt) * 16 + l16; \
    f32x4 vacc = {0.f, 0.f, 0.f, 0.f}; \
    f32x4 gacc = {0.f, 0.f, 0.f, 0.f}; \
    bf16x8 wb0 = *(const bf16x8*)(sW1aT + jrow * 72 + quad * 8); \
    bf16x8 wb1 = *(const bf16x8*)(sW1aT + jrow * 72 + 32 + quad * 8); \
    vacc = MFMA16(ae0, wb0, vacc); \
    vacc = MFMA16(ae1, wb1, vacc); \
    bf16x8 aw0 = *(const bf16x8*)(sW2U + jrow * 72 + quad * 8); \
    bf16x8 aw1 = *(const bf16x8*)(sW2U + jrow * 72 + 32 + quad * 8); \
    gacc = MFMA16(aw0, ae0, gacc); \
    gacc = MFMA16(aw1, ae1, gacc); \
    scr[(rr + 0) * 17 + l16] = gacc[0]; \
    scr[(rr + 1) * 17 + l16] = gacc[1]; \
    scr[(rr + 2) * 17 + l16] = gacc[2]; \
    scr[(rr + 3) * 17 + l16] = gacc[3]; \
    __syncthreads(); \
    ghvp[(jt) * 2 + 0] = pack2(scr[l16 * 17 + rr + 0] * vacc[0], \
                               scr[l16 * 17 + rr + 1] * vacc[1]); \
    ghvp[(jt) * 2 + 1] = pack2(scr[l16 * 17 + rr + 2] * vacc[2], \
                               scr[l16 * 17 + rr + 3] * vacc[3]); \
    __syncthreads(); }
    PRE(0) PRE(1) PRE(2) PRE(3) PRE(4) PRE(5) PRE(6) PRE(7)

    // ---------------- load z state for own col-half ----------------
    float z[2][4];  // [ct][rg]: row rr+rg, col colb+ct*16+l16
#define LDZ(ct, rg) z[ct][rg] = Yg[(row0 + rr + (rg)) * 64 + colb + (ct) * 16 + l16];
    LDZ(0,0) LDZ(0,1) LDZ(0,2) LDZ(0,3) LDZ(1,0) LDZ(1,1) LDZ(1,2) LDZ(1,3)

    // b2 for own cols
    const float bb0 = sB2[colb + l16];
    const float bb1 = sB2[colb + 16 + l16];

    // ---------------- phase-2: overwrite union region with W2^T ----------------
    __syncthreads();
    for (int idx = tid; idx < 256 * 64; idx += 512) {
        int j = idx >> 6, d = idx & 63;
        sW2U[d * 264 + j] = (__bf16)W2g[idx];  // [d][j], j-contig per d
    }
    __syncthreads();

    const float dt = 0.125f;
    u32 kp[6][4];   // [stage][ct*2+pr]: bf16x2 of k rows (rr+pr*2, rr+pr*2+1)
    float lp0 = 0.f, lp1 = 0.f, lp2 = 0.f, lp3 = 0.f;  // own-j-half partial

#define KLO(s, i) frombits(kp[s][i] & 0xffffu)
#define KHI(s, i) frombits(kp[s][i] >> 16)

#define STY(ct, pr, a0, a1) \
    yb[(rr + (pr)*2 + 0) * 72 + colb + (ct)*16 + l16] = (__bf16)(z[ct][(pr)*2 + 0] + dt*(a0)); \
    yb[(rr + (pr)*2 + 1) * 72 + colb + (ct)*16 + l16] = (__bf16)(z[ct][(pr)*2 + 1] + dt*(a1));

#define B0(ct, pr) STY(ct, pr, 0.f, 0.f)
#define B1(ct, pr) STY(ct, pr, 0.2f*KLO(0,(ct)*2+(pr)), 0.2f*KHI(0,(ct)*2+(pr)))
#define B2(ct, pr) STY(ct, pr, \
    0.075f*KLO(0,(ct)*2+(pr)) + 0.225f*KLO(1,(ct)*2+(pr)), \
    0.075f*KHI(0,(ct)*2+(pr)) + 0.225f*KHI(1,(ct)*2+(pr)))
#define B3(ct, pr) STY(ct, pr, \
    (44.f/45.f)*KLO(0,(ct)*2+(pr)) + (-56.f/15.f)*KLO(1,(ct)*2+(pr)) + (32.f/9.f)*KLO(2,(ct)*2+(pr)), \
    (44.f/45.f)*KHI(0,(ct)*2+(pr)) + (-56.f/15.f)*KHI(1,(ct)*2+(pr)) + (32.f/9.f)*KHI(2,(ct)*2+(pr)))
#define B4(ct, pr) STY(ct, pr, \
    (19372.f/6561.f)*KLO(0,(ct)*2+(pr)) + (-25360.f/2187.f)*KLO(1,(ct)*2+(pr)) + \
    (64448.f/6561.f)*KLO(2,(ct)*2+(pr)) + (-212.f/729.f)*KLO(3,(ct)*2+(pr)), \
    (19372.f/6561.f)*KHI(0,(ct)*2+(pr)) + (-25360.f/2187.f)*KHI(1,(ct)*2+(pr)) + \
    (64448.f/6561.f)*KHI(2,(ct)*2+(pr)) + (-212.f/729.f)*KHI(3,(ct)*2+(pr)))
#define B5(ct, pr) STY(ct, pr, \
    (9017.f/3168.f)*KLO(0,(ct)*2+(pr)) + (-355.f/33.f)*KLO(1,(ct)*2+(pr)) + \
    (46732.f/5247.f)*KLO(2,(ct)*2+(pr)) + (49.f/176.f)*KLO(3,(ct)*2+(pr)) + \
    (-5103.f/18656.f)*KLO(4,(ct)*2+(pr)), \
    (9017.f/3168.f)*KHI(0,(ct)*2+(pr)) + (-355.f/33.f)*KHI(1,(ct)*2+(pr)) + \
    (46732.f/5247.f)*KHI(2,(ct)*2+(pr)) + (49.f/176.f)*KHI(3,(ct)*2+(pr)) + \
    (-5103.f/18656.f)*KHI(4,(ct)*2+(pr)))

#define BUILD(M) M(0,0) M(0,1) M(1,0) M(1,1)

#define JT_BODY(jt) { \
    const int jrow = jb + (jt) * 16 + l16; \
    f32x4 ua = {0.f, 0.f, 0.f, 0.f}; \
    bf16x8 wb0 = *(const bf16x8*)(sW1aT + jrow * 72 + quad * 8); \
    ua = MFMA16(a10, wb0, ua); \
    bf16x8 wb1 = *(const bf16x8*)(sW1aT + jrow * 72 + 32 + quad * 8); \
    ua = MFMA16(a11, wb1, ua); \
    const float bw = sB1[jrow] + ti * sW1t[jrow]; \
    float h0 = fast_tanh(ua[0] + bw), h1 = fast_tanh(ua[1] + bw); \
    float h2 = fast_tanh(ua[2] + bw), h3 = fast_tanh(ua[3] + bw); \
    dv0 += frombits(ghvp[(jt)*2 + 0] & 0xffffu) * (1.f - h0*h0); \
    dv1 += frombits(ghvp[(jt)*2 + 0] >> 16)     * (1.f - h1*h1); \
    dv2 += frombits(ghvp[(jt)*2 + 1] & 0xffffu) * (1.f - h2*h2); \
    dv3 += frombits(ghvp[(jt)*2 + 1] >> 16)     * (1.f - h3*h3); \
    __bf16* hw = hb + jrow; \
    hw[(rr + 0) * 264] = (__bf16)h0; hw[(rr + 1) * 264] = (__bf16)h1; \
    hw[(rr + 2) * 264] = (__bf16)h2; hw[(rr + 3) * 264] = (__bf16)h3; }

#define KK_BODY(kk) { \
    bf16x8 a2 = *(const bf16x8*)(hb + l16 * 264 + (kk)*32 + quad * 8); \
    bf16x8 w0 = *(const bf16x8*)(sW2U + (colb + 0 + l16) * 264 + (kk)*32 + quad * 8); \
    fa0 = MFMA16(a2, w0, fa0); \
    bf16x8 w1 = *(const bf16x8*)(sW2U + (colb + 16 + l16) * 264 + (kk)*32 + quad * 8); \
    fa1 = MFMA16(a2, w1, fa1); }

#define STAGE(st, CTI, DTB) { \
    __syncthreads(); \
    const float ti = t0 + (CTI) * dt; \
    bf16x8 a10 = *(const bf16x8*)(yb + l16 * 72 + quad * 8); \
    bf16x8 a11 = *(const bf16x8*)(yb + l16 * 72 + 32 + quad * 8); \
    float dv0 = 0.f, dv1 = 0.f, dv2 = 0.f, dv3 = 0.f; \
    JT_BODY(0) JT_BODY(1) JT_BODY(2) JT_BODY(3) \
    JT_BODY(4) JT_BODY(5) JT_BODY(6) JT_BODY(7) \
    __syncthreads(); \
    f32x4 fa0 = {0.f,0.f,0.f,0.f}, fa1 = {0.f,0.f,0.f,0.f}; \
    KK_BODY(0) KK_BODY(1) KK_BODY(2) KK_BODY(3) \
    KK_BODY(4) KK_BODY(5) KK_BODY(6) KK_BODY(7) \
    kp[st][0] = pack2(fa0[0] + bb0, fa0[1] + bb0); \
    kp[st][1] = pack2(fa0[2] + bb0, fa0[3] + bb0); \
    kp[st][2] = pack2(fa1[0] + bb1, fa1[1] + bb1); \
    kp[st][3] = pack2(fa1[2] + bb1, fa1[3] + bb1); \
    dv0 += __shfl_xor(dv0, 1); dv0 += __shfl_xor(dv0, 2); \
    dv0 += __shfl_xor(dv0, 4); dv0 += __shfl_xor(dv0, 8); \
    dv1 += __shfl_xor(dv1, 1); dv1 += __shfl_xor(dv1, 2); \
    dv1 += __shfl_xor(dv1, 4); dv1 += __shfl_xor(dv1, 8); \
    dv2 += __shfl_xor(dv2, 1); dv2 += __shfl_xor(dv2, 2); \
    dv2 += __shfl_xor(dv2, 4); dv2 += __shfl_xor(dv2, 8); \
    dv3 += __shfl_xor(dv3, 1); dv3 += __shfl_xor(dv3, 2); \
    dv3 += __shfl_xor(dv3, 4); dv3 += __shfl_xor(dv3, 8); \
    lp0 -= (DTB) * dv0; lp1 -= (DTB) * dv1; \
    lp2 -= (DTB) * dv2; lp3 -= (DTB) * dv3; }

#define COMB(ct, pr) { \
    float s0 = (35.f/384.f)*KLO(0,(ct)*2+(pr)) + (500.f/1113.f)*KLO(2,(ct)*2+(pr)) \
             + (125.f/192.f)*KLO(3,(ct)*2+(pr)) + (-2187.f/6784.f)*KLO(4,(ct)*2+(pr)) \
             + (11.f/84.f)*KLO(5,(ct)*2+(pr)); \
    float s1 = (35.f/384.f)*KHI(0,(ct)*2+(pr)) + (500.f/1113.f)*KHI(2,(ct)*2+(pr)) \
             + (125.f/192.f)*KHI(3,(ct)*2+(pr)) + (-2187.f/6784.f)*KHI(4,(ct)*2+(pr)) \
             + (11.f/84.f)*KHI(5,(ct)*2+(pr)); \
    z[ct][(pr)*2 + 0] += dt * s0; \
    z[ct][(pr)*2 + 1] += dt * s1; }

    for (int step = 0; step < 8; ++step) {
        const float t0 = dt * (float)step;
        BUILD(B0) STAGE(0, 0.f,     dt*(35.f/384.f))
        BUILD(B1) STAGE(1, 0.2f,    dt*0.f)
        BUILD(B2) STAGE(2, 0.3f,    dt*(500.f/1113.f))
        BUILD(B3) STAGE(3, 0.8f,    dt*(125.f/192.f))
        BUILD(B4) STAGE(4, 8.f/9.f, dt*(-2187.f/6784.f))
        BUILD(B5) STAGE(5, 1.f,     dt*(11.f/84.f))
        BUILD(COMB)
    }

    // ---------------- epilogue ----------------
    float ss0 = 0.f, ss1 = 0.f, ss2 = 0.f, ss3 = 0.f;
#define EPI(ct) { \
    Og[(row0 + rr + 0) * 64 + colb + (ct)*16 + l16] = z[ct][0]; ss0 += z[ct][0]*z[ct][0]; \
    Og[(row0 + rr + 1) * 64 + colb + (ct)*16 + l16] = z[ct][1]; ss1 += z[ct][1]*z[ct][1]; \
    Og[(row0 + rr + 2) * 64 + colb + (ct)*16 + l16] = z[ct][2]; ss2 += z[ct][2]*z[ct][2]; \
    Og[(row0 + rr + 3) * 64 + colb + (ct)*16 + l16] = z[ct][3]; ss3 += z[ct][3]*z[ct][3]; }
    EPI(0) EPI(1)

    ss0 += __shfl_xor(ss0, 1); ss0 += __shfl_xor(ss0, 2);
    ss0 += __shfl_xor(ss0, 4); ss0 += __shfl_xor(ss0, 8);
    ss1 += __shfl_xor(ss1, 1); ss1 += __shfl_xor(ss1, 2);
    ss1 += __shfl_xor(ss1, 4); ss1 += __shfl_xor(ss1, 8);
    ss2 += __shfl_xor(ss2, 1); ss2 += __shfl_xor(ss2, 2);
    ss2 += __shfl_xor(ss2, 4); ss2 += __shfl_xor(ss2, 8);
    ss3 += __shfl_xor(ss3, 1); ss3 += __shfl_xor(ss3, 2);
    ss3 += __shfl_xor(ss3, 4); ss3 += __shfl_xor(ss3, 8);

    if (l16 == 0) {
        sRedSS[wave * 16 + rr + 0] = ss0;  sRedLP[wave * 16 + rr + 0] = lp0;
        sRedSS[wave * 16 + rr + 1] = ss1;  sRedLP[wave * 16 + rr + 1] = lp1;
        sRedSS[wave * 16 + rr + 2] = ss2;  sRedLP[wave * 16 + rr + 2] = lp2;
        sRedSS[wave * 16 + rr + 3] = ss3;  sRedLP[wave * 16 + rr + 3] = lp3;
    }
    __syncthreads();
    if (P == 0 && l16 == 0) {
        const float CLOG = -58.8120661f;  // -32*ln(2*pi)
        #pragma unroll
        for (int g = 0; g < 4; ++g) {
            float sfull = sRedSS[wave * 16 + rr + g] + sRedSS[(wave + 1) * 16 + rr + g];
            float lfull = sRedLP[wave * 16 + rr + g] + sRedLP[(wave + 1) * 16 + rr + g];
            Og[32768 * 64 + row0 + rr + g] = CLOG - 0.5f * sfull - lfull;
        }
    }
}

extern "C" void kernel_launch(void* const* d_in, const int* in_sizes, int n_in,
                              void* d_out, int out_size, void* d_ws, size_t ws_size,
                              hipStream_t stream) {
    const float* Yg  = (const float*)d_in[0];
    const float* Eg  = (const float*)d_in[1];
    const float* W1g = (const float*)d_in[2];  // [65][256]
    const float* b1g = (const float*)d_in[3];
    const float* W2g = (const float*)d_in[4];  // [256][64]
    const float* b2g = (const float*)d_in[5];
    float* Og = (float*)d_out;                 // z (32768*64) then log_px (32768)
    cnf_kernel<<<dim3(512), dim3(512), 0, stream>>>(Yg, Eg, W1g, b1g, W2g, b2g, Og);
}

// Round 5
// 326.346 us; speedup vs baseline: 5.6717x; 1.1358x over previous
//
#include <hip/hip_runtime.h>

// CNF forward: 8 fixed dopri5 steps x 6 stages, rows independent.
// R5: 4-wave groups own 16 rows; wave Q owns j in [Q*64,Q*64+64) and output
// cols [Q*16,Q*16+16). All W1/W2 MFMA fragments register-cached (64 VGPRs) --
// R4 spent ~58% of its LDS-pipe cycles re-reading constant weight frags.
// matmul-1 operand order flipped (A=W1^T, B=y) so h/y/dv layouts vectorize:
// h store = 1 ds_write_b64 per tile (was 4 scalar b16), y store = 1 b64,
// dv/lp = 1 reg + 2 shfls. Bias via per-stage sBW precompute (broadcast b128).
// 1024 blocks x 512 threads (2 groups/block, 32 rows/block).

typedef __bf16 bf16x8 __attribute__((ext_vector_type(8)));
typedef __bf16 bf16x4 __attribute__((ext_vector_type(4)));
typedef float  f32x4  __attribute__((ext_vector_type(4)));
typedef unsigned int u32;

#define MFMA16(a, b, c) __builtin_amdgcn_mfma_f32_16x16x32_bf16((a), (b), (c), 0, 0, 0)

__device__ __forceinline__ u32 bfbits(float x) {
    __bf16 b = (__bf16)x;                      // RNE fp32->bf16
    return (u32)__builtin_bit_cast(unsigned short, b);
}
__device__ __forceinline__ float frombits(u32 u16) {
    return __builtin_bit_cast(float, u16 << 16);
}
__device__ __forceinline__ u32 pack2(float lo, float hi) {
    return bfbits(lo) | (bfbits(hi) << 16);
}
__device__ __forceinline__ float fast_tanh(float x) {
    float e = __expf(2.0f * x);
    return 1.0f - 2.0f * __builtin_amdgcn_rcpf(e + 1.0f);
}

extern "C" __global__ __attribute__((amdgpu_waves_per_eu(2, 2))) void
__launch_bounds__(512)
cnf_kernel(const float* __restrict__ Yg, const float* __restrict__ Eg,
           const float* __restrict__ W1g, const float* __restrict__ b1g,
           const float* __restrict__ W2g, const float* __restrict__ b2g,
           float* __restrict__ Og)
{
    // ---- LDS (~110 KB; 1 WG/CU, 2 waves/EU) ----
    __shared__ __align__(16) __bf16 sW1aT[256 * 72];   // [j][d] W1a^T (init only)
    __shared__ __align__(16) __bf16 sW2U[256 * 72];    // ph1: W2 [j*72+d]; ph2: W2^T [d*264+j]
    __shared__ __align__(16) __bf16 sY[2][16 * 72];    // per-GROUP y buf [batch][d]
    __shared__ __align__(16) __bf16 sH[2][16 * 264];   // per-GROUP h buf [batch][j]
    __shared__ __align__(16) float  sScr[8][16 * 17 + 4]; // per-wave transpose scratch (init)
    __shared__ float sB1f[256], sW1tf[256], sBW[256];
    __shared__ float sRedSS[128], sRedLP[128];

    const int tid  = threadIdx.x;
    const int wave = tid >> 6;
    const int lane = tid & 63;
    const int quad = lane >> 4;
    const int l16  = lane & 15;
    const int grp  = wave >> 2;       // 2 groups of 4 waves
    const int Q    = wave & 3;        // wave's slot within group
    const int colb = Q * 16;          // own output-col tile base
    const int jb   = Q * 64;          // own hidden-j base (4 tiles of 16)
    const int row  = blockIdx.x * 32 + grp * 16 + l16;  // this lane's batch row

    // ---------------- phase-1 weight staging ----------------
    for (int idx = tid; idx < 64 * 256; idx += 512) {         // W1a^T [j][d]
        int d = idx >> 8, j = idx & 255;
        sW1aT[j * 72 + d] = (__bf16)W1g[idx];
    }
    for (int idx = tid; idx < 256 * 64; idx += 512) {         // W2 row-major [j][d]
        int j = idx >> 6, d = idx & 63;
        sW2U[j * 72 + d] = (__bf16)W2g[idx];
    }
    for (int j = tid; j < 256; j += 512) { sB1f[j] = b1g[j]; sW1tf[j] = W1g[64 * 256 + j]; }
    __syncthreads();

    // ---------------- register-cache W1 fragments (A-operand: [m=j][k=d]) ----------------
    bf16x8 w1f[8];   // [tile*2 + half]
#define LDW1(t) \
    w1f[(t)*2 + 0] = *(const bf16x8*)(sW1aT + (jb + (t)*16 + l16) * 72 + quad * 8); \
    w1f[(t)*2 + 1] = *(const bf16x8*)(sW1aT + (jb + (t)*16 + l16) * 72 + 32 + quad * 8);
    LDW1(0) LDW1(1) LDW1(2) LDW1(3)

    // ---------------- e fragments direct from global ----------------
    // ae: lane (l16=batch, quad) holds e[row][d = quad*8 + i] (+32 for ae1)
    bf16x8 ae0, ae1;
    {
        f32x4 ea = *(const f32x4*)(Eg + row * 64 + quad * 8);
        f32x4 eb = *(const f32x4*)(Eg + row * 64 + quad * 8 + 4);
        f32x4 ec = *(const f32x4*)(Eg + row * 64 + 32 + quad * 8);
        f32x4 ed = *(const f32x4*)(Eg + row * 64 + 32 + quad * 8 + 4);
        ae0[0]=(__bf16)ea[0]; ae0[1]=(__bf16)ea[1]; ae0[2]=(__bf16)ea[2]; ae0[3]=(__bf16)ea[3];
        ae0[4]=(__bf16)eb[0]; ae0[5]=(__bf16)eb[1]; ae0[6]=(__bf16)eb[2]; ae0[7]=(__bf16)eb[3];
        ae1[0]=(__bf16)ec[0]; ae1[1]=(__bf16)ec[1]; ae1[2]=(__bf16)ec[2]; ae1[3]=(__bf16)ec[3];
        ae1[4]=(__bf16)ed[0]; ae1[5]=(__bf16)ed[1]; ae1[6]=(__bf16)ed[2]; ae1[7]=(__bf16)ed[3];
    }

    // ---------------- precompute ghv[j][batch] = gh0 .* v, layout j=quad*4+rg, batch=l16 ----
    float* scr = sScr[wave];
    u32 ghvp[8];   // [tile*2 + pair]
#define PRE(t) { \
    f32x4 vacc = {0.f, 0.f, 0.f, 0.f}; \
    f32x4 gacc = {0.f, 0.f, 0.f, 0.f}; \
    /* v = e@W1a: A=e[m=batch][k=d], B=W1a[k=d][n=j] -> C[batch=quad*4+rg][j=l16] */ \
    vacc = MFMA16(ae0, w1f[(t)*2 + 0], vacc); \
    vacc = MFMA16(ae1, w1f[(t)*2 + 1], vacc); \
    /* gh0^T = W2@e^T: A=W2[m=j][k=d], B=e^T[k=d][n=batch] -> C[j=quad*4+rg][batch=l16] */ \
    bf16x8 aw0 = *(const bf16x8*)(sW2U + (jb + (t)*16 + l16) * 72 + quad * 8); \
    bf16x8 aw1 = *(const bf16x8*)(sW2U + (jb + (t)*16 + l16) * 72 + 32 + quad * 8); \
    gacc = MFMA16(aw0, ae0, gacc); \
    gacc = MFMA16(aw1, ae1, gacc); \
    /* transpose vacc via scratch to [j=quad*4+rg][batch=l16] */ \
    scr[(quad*4 + 0) * 17 + l16] = vacc[0]; \
    scr[(quad*4 + 1) * 17 + l16] = vacc[1]; \
    scr[(quad*4 + 2) * 17 + l16] = vacc[2]; \
    scr[(quad*4 + 3) * 17 + l16] = vacc[3]; \
    __syncthreads(); \
    float v0 = scr[l16 * 17 + quad*4 + 0]; \
    float v1 = scr[l16 * 17 + quad*4 + 1]; \
    float v2 = scr[l16 * 17 + quad*4 + 2]; \
    float v3 = scr[l16 * 17 + quad*4 + 3]; \
    ghvp[(t)*2 + 0] = pack2(gacc[0] * v0, gacc[1] * v1); \
    ghvp[(t)*2 + 1] = pack2(gacc[2] * v2, gacc[3] * v3); \
    __syncthreads(); }
    PRE(0) PRE(1) PRE(2) PRE(3)

    // ---------------- z state + b2, direct global (lane layout: batch=l16, d=colb+quad*4+rg) ----
    f32x4 zv  = *(const f32x4*)(Yg + row * 64 + colb + quad * 4);
    f32x4 bb2 = *(const f32x4*)(b2g + colb + quad * 4);

    // ---------------- phase-2: rewrite sW2U as W2^T [d*264 + j] ----------------
    for (int idx = tid; idx < 256 * 64; idx += 512) {
        int j = idx >> 6, d = idx & 63;
        sW2U[d * 264 + j] = (__bf16)W2g[idx];
    }
    __syncthreads();

    // ---------------- register-cache W2^T fragments (A-operand: [m=dout][k=j]) ----------------
    bf16x8 w2f[8];   // [chunk]
#define LDW2(c) w2f[c] = *(const bf16x8*)(sW2U + (colb + l16) * 264 + (c)*32 + quad * 8);
    LDW2(0) LDW2(1) LDW2(2) LDW2(3) LDW2(4) LDW2(5) LDW2(6) LDW2(7)

    __bf16* yb = sY[grp];
    __bf16* hb = sH[grp];

    const float dt = 0.125f;
    u32 kp[6][2];     // k_dz bf16x2: [stage][pair], d = colb + quad*4 + {0..3}
    float lp = 0.f;   // own-j partial of dlogp (batch = l16)

#define KV(s, g) frombits(((g) & 1) ? (kp[s][(g)>>1] >> 16) : (kp[s][(g)>>1] & 0xffffu))

#define S1A(g) (0.2f*KV(0,g))
#define S2A(g) (0.075f*KV(0,g) + 0.225f*KV(1,g))
#define S3A(g) ((44.f/45.f)*KV(0,g) + (-56.f/15.f)*KV(1,g) + (32.f/9.f)*KV(2,g))
#define S4A(g) ((19372.f/6561.f)*KV(0,g) + (-25360.f/2187.f)*KV(1,g) + \
                (64448.f/6561.f)*KV(2,g) + (-212.f/729.f)*KV(3,g))
#define S5A(g) ((9017.f/3168.f)*KV(0,g) + (-355.f/33.f)*KV(1,g) + \
                (46732.f/5247.f)*KV(2,g) + (49.f/176.f)*KV(3,g) + (-5103.f/18656.f)*KV(4,g))
#define CBA(g) ((35.f/384.f)*KV(0,g) + (500.f/1113.f)*KV(2,g) + (125.f/192.f)*KV(3,g) + \
                (-2187.f/6784.f)*KV(4,g) + (11.f/84.f)*KV(5,g))

    // matmul-1 tile: ua init = bw (bias in accumulator); h packed b64 to hb
#define MM1T(t) { \
    f32x4 ua = *(const f32x4*)(sBW + jb + (t)*16 + quad * 4); \
    ua = MFMA16(w1f[(t)*2 + 0], a10, ua); \
    ua = MFMA16(w1f[(t)*2 + 1], a11, ua); \
    float h0 = fast_tanh(ua[0]), h1 = fast_tanh(ua[1]); \
    float h2 = fast_tanh(ua[2]), h3 = fast_tanh(ua[3]); \
    u32 g0 = ghvp[(t)*2 + 0], g1 = ghvp[(t)*2 + 1]; \
    dv += frombits(g0 & 0xffffu) * (1.f - h0*h0); \
    dv += frombits(g0 >> 16)     * (1.f - h1*h1); \
    dv += frombits(g1 & 0xffffu) * (1.f - h2*h2); \
    dv += frombits(g1 >> 16)     * (1.f - h3*h3); \
    bf16x4 hv; hv[0]=(__bf16)h0; hv[1]=(__bf16)h1; hv[2]=(__bf16)h2; hv[3]=(__bf16)h3; \
    *(bf16x4*)(hb + l16 * 264 + jb + (t)*16 + quad * 4) = hv; }

#define MM2C(c) { \
    bf16x8 hf = *(const bf16x8*)(hb + l16 * 264 + (c)*32 + quad * 8); \
    fa = MFMA16(w2f[c], hf, fa); }

#define STAGE(st, CTI, DTB, A0, A1, A2, A3) { \
    const float ti = t0 + (CTI) * dt; \
    { \
        bf16x4 yv; \
        yv[0] = (__bf16)(zv[0] + dt * (A0)); \
        yv[1] = (__bf16)(zv[1] + dt * (A1)); \
        yv[2] = (__bf16)(zv[2] + dt * (A2)); \
        yv[3] = (__bf16)(zv[3] + dt * (A3)); \
        *(bf16x4*)(yb + l16 * 72 + colb + quad * 4) = yv; \
    } \
    if (tid < 256) sBW[tid] = sB1f[tid] + ti * sW1tf[tid]; \
    __syncthreads(); \
    bf16x8 a10 = *(const bf16x8*)(yb + l16 * 72 + quad * 8); \
    bf16x8 a11 = *(const bf16x8*)(yb + l16 * 72 + 32 + quad * 8); \
    float dv = 0.f; \
    MM1T(0) MM1T(1) MM1T(2) MM1T(3) \
    __syncthreads(); \
    f32x4 fa = bb2; \
    MM2C(0) MM2C(1) MM2C(2) MM2C(3) MM2C(4) MM2C(5) MM2C(6) MM2C(7) \
    kp[st][0] = pack2(fa[0], fa[1]); \
    kp[st][1] = pack2(fa[2], fa[3]); \
    dv += __shfl_xor(dv, 16); \
    dv += __shfl_xor(dv, 32); \
    lp -= (DTB) * dv; }

    for (int step = 0; step < 8; ++step) {
        const float t0 = dt * (float)step;
        STAGE(0, 0.f,     dt*(35.f/384.f),    0.f,    0.f,    0.f,    0.f)
        STAGE(1, 0.2f,    0.f,                S1A(0), S1A(1), S1A(2), S1A(3))
        STAGE(2, 0.3f,    dt*(500.f/1113.f),  S2A(0), S2A(1), S2A(2), S2A(3))
        STAGE(3, 0.8f,    dt*(125.f/192.f),   S3A(0), S3A(1), S3A(2), S3A(3))
        STAGE(4, 8.f/9.f, dt*(-2187.f/6784.f),S4A(0), S4A(1), S4A(2), S4A(3))
        STAGE(5, 1.f,     dt*(11.f/84.f),     S5A(0), S5A(1), S5A(2), S5A(3))
        zv[0] += dt * CBA(0);
        zv[1] += dt * CBA(1);
        zv[2] += dt * CBA(2);
        zv[3] += dt * CBA(3);
    }

    // ---------------- epilogue ----------------
    *(f32x4*)(Og + row * 64 + colb + quad * 4) = zv;
    float ss = zv[0]*zv[0] + zv[1]*zv[1] + zv[2]*zv[2] + zv[3]*zv[3];
    ss += __shfl_xor(ss, 16);
    ss += __shfl_xor(ss, 32);
    if (quad == 0) {
        sRedSS[wave * 16 + l16] = ss;
        sRedLP[wave * 16 + l16] = lp;
    }
    __syncthreads();
    if (Q == 0 && quad == 0) {
        const float CLOG = -58.8120661f;  // -32*ln(2*pi)
        float sfull = sRedSS[(grp*4 + 0)*16 + l16] + sRedSS[(grp*4 + 1)*16 + l16]
                    + sRedSS[(grp*4 + 2)*16 + l16] + sRedSS[(grp*4 + 3)*16 + l16];
        float lfull = sRedLP[(grp*4 + 0)*16 + l16] + sRedLP[(grp*4 + 1)*16 + l16]
                    + sRedLP[(grp*4 + 2)*16 + l16] + sRedLP[(grp*4 + 3)*16 + l16];
        Og[32768 * 64 + row] = CLOG - 0.5f * sfull - lfull;
    }
}

extern "C" void kernel_launch(void* const* d_in, const int* in_sizes, int n_in,
                              void* d_out, int out_size, void* d_ws, size_t ws_size,
                              hipStream_t stream) {
    const float* Yg  = (const float*)d_in[0];
    const float* Eg  = (const float*)d_in[1];
    const float* W1g = (const float*)d_in[2];  // [65][256]
    const float* b1g = (const float*)d_in[3];
    const float* W2g = (const float*)d_in[4];  // [256][64]
    const float* b2g = (const float*)d_in[5];
    float* Og = (float*)d_out;                 // z (32768*64) then log_px (32768)
    cnf_kernel<<<dim3(1024), dim3(512), 0, stream>>>(Yg, Eg, W1g, b1g, W2g, b2g, Og);
}